// Round 4
// baseline (194.590 us; speedup 1.0000x reference)
//
#include <hip/hip_runtime.h>

#define T_LEN 2048
#define DIM 2048
#define NH 16
#define HD 128
#define QKV_LD 6144   // 3*DIM

typedef __attribute__((ext_vector_type(8))) short short8;
typedef __attribute__((ext_vector_type(4))) float f32x4;
typedef __attribute__((ext_vector_type(4))) float float4v;
typedef __attribute__((ext_vector_type(4))) unsigned short ushort4v;
typedef __attribute__((ext_vector_type(2))) unsigned int uint2v;

static __device__ __forceinline__ unsigned short f2bf(float f) {
  unsigned u = __builtin_bit_cast(unsigned, f);
  u += 0x7fffu + ((u >> 16) & 1u);   // round-to-nearest-even
  return (unsigned short)(u >> 16);
}

static __device__ __forceinline__ float max3f(float a, float b, float c) {
  return fmaxf(fmaxf(a, b), c);      // clang fuses to v_max3_f32
}

static __device__ __forceinline__ f32x4 mfma16(short8 a, short8 b, f32x4 c) {
  return __builtin_amdgcn_mfma_f32_16x16x32_bf16(a, b, c, 0, 0, 0);
}

#define GLDS16(SRC, DST)                                                            \
  __builtin_amdgcn_global_load_lds((__attribute__((address_space(1))) void*)(SRC),  \
                                   (__attribute__((address_space(3))) void*)(DST),  \
                                   16, 0, 0)

// ---------------------------------------------------------------- cast fp32->bf16
__global__ void cast_f32_bf16(const float* __restrict__ in,
                              unsigned short* __restrict__ out, int n4) {
  int i = blockIdx.x * blockDim.x + threadIdx.x;
  const int stride = gridDim.x * blockDim.x;
  for (; i < n4; i += stride) {
    float4v f = ((const float4v*)in)[i];
    ushort4v o;
    o.x = f2bf(f.x); o.y = f2bf(f.y); o.z = f2bf(f.z); o.w = f2bf(f.w);
    ((ushort4v*)out)[i] = o;
  }
}

// ---------------------------------------------------------------- GEMM: C = A * B^T
// A [M][K] bf16 row-major, B [N][K] bf16 row-major, C [M][N] (bf16 or f32).
// 128x128 tile, BK=64, 4 waves (each 64x64), global_load_lds staging,
// LDS rows 128B with byte ^= ((row&7)<<4) swizzle (pre-swizzled global source).
template <int OUT_BF16>
__global__ __launch_bounds__(256) void gemm_bt_128(
    const unsigned short* __restrict__ A,
    const unsigned short* __restrict__ B,
    void* __restrict__ Cv, int M, int N, int K) {
  __shared__ unsigned short As[128 * 64];
  __shared__ unsigned short Bs[128 * 64];
  const int tid = threadIdx.x;
  const int wave = tid >> 6;
  const int lane = tid & 63;
  const int l15 = lane & 15, l16 = lane >> 4;
  const int bm = blockIdx.y * 128;
  const int bn = blockIdx.x * 128;
  const int wr = wave >> 1, wc = wave & 1;

  f32x4 acc[4][4] = {};

  // staging source (element offsets within the 128x64 tile), inverse-swizzled
  int srow[4], scol[4];
#pragma unroll
  for (int i = 0; i < 4; ++i) {
    int lin = i * 4096 + tid * 16;     // byte index, linear LDS order
    int row = lin >> 7;                // 128B rows
    int cb = lin & 127;
    srow[i] = row;
    scol[i] = (cb ^ ((row & 7) << 4)) >> 1;
  }

  for (int k0 = 0; k0 < K; k0 += 64) {
#pragma unroll
    for (int i = 0; i < 4; ++i) {
      GLDS16(A + (size_t)(bm + srow[i]) * K + k0 + scol[i], As + i * 2048 + wave * 512);
      GLDS16(B + (size_t)(bn + srow[i]) * K + k0 + scol[i], Bs + i * 2048 + wave * 512);
    }
    __syncthreads();
#pragma unroll
    for (int kk = 0; kk < 2; ++kk) {
      const int cb = kk * 64 + l16 * 16;
      short8 af[4], bfr[4];
#pragma unroll
      for (int m = 0; m < 4; ++m) {
        int row = wr * 64 + m * 16 + l15;
        af[m] = *(const short8*)((const char*)As + row * 128 + (cb ^ ((row & 7) << 4)));
      }
#pragma unroll
      for (int n = 0; n < 4; ++n) {
        int row = wc * 64 + n * 16 + l15;
        bfr[n] = *(const short8*)((const char*)Bs + row * 128 + (cb ^ ((row & 7) << 4)));
      }
#pragma unroll
      for (int m = 0; m < 4; ++m)
#pragma unroll
        for (int n = 0; n < 4; ++n)
          acc[m][n] = mfma16(af[m], bfr[n], acc[m][n]);
    }
    __syncthreads();
  }

  // epilogue: C/D layout col=lane&15, row=(lane>>4)*4+j  [m89-verified]
#pragma unroll
  for (int m = 0; m < 4; ++m)
#pragma unroll
    for (int n = 0; n < 4; ++n) {
      int row = bm + wr * 64 + m * 16 + l16 * 4;
      int col = bn + wc * 64 + n * 16 + l15;
#pragma unroll
      for (int j = 0; j < 4; ++j) {
        if (OUT_BF16)
          ((unsigned short*)Cv)[(size_t)(row + j) * N + col] = f2bf(acc[m][n][j]);
        else
          ((float*)Cv)[(size_t)(row + j) * N + col] = acc[m][n][j];
      }
    }
}

// ---------------------------------------------------------------- V transpose
// qkv[s][4096 + h*128 + d] -> vt[h][d][s], 64-s tile per block, swizzled LDS.
__global__ __launch_bounds__(256) void transpose_v(
    const unsigned short* __restrict__ qkv, unsigned short* __restrict__ vt) {
  __shared__ unsigned short t[64 * 128];
  const int tid = threadIdx.x;
  const int h = blockIdx.y;
  const int s0 = blockIdx.x * 64;
#pragma unroll
  for (int i = 0; i < 4; ++i) {
    int lin = i * 2048 + tid * 8;    // element index in 64x128 tile
    int row = lin >> 7, col = lin & 127;
    char* dst = (char*)t + row * 256 + ((col * 2) ^ (((row >> 3) & 7) << 4));
    *(short8*)dst =
        *(const short8*)(qkv + (size_t)(s0 + row) * QKV_LD + 2 * DIM + h * HD + col);
  }
  __syncthreads();
#pragma unroll
  for (int i2 = 0; i2 < 4; ++i2) {
    int d = (tid >> 3) + i2 * 32;
    int sb = (tid & 7) * 8;
    short8 v;
#pragma unroll
    for (int j = 0; j < 8; ++j) {
      int s = sb + j;
      v[j] = *(const short*)((const char*)t + s * 256 + ((d * 2) ^ (((s >> 3) & 7) << 4)));
    }
    *(short8*)(vt + ((size_t)h * HD + d) * T_LEN + s0 + sb) = v;
  }
}

// ---------------------------------------------------------------- flash attention
// Block = 4 waves; wave w owns 16 Q rows. SINGLE-buffered K/V (R2 proved dbuf
// buys nothing at 2 waves/SIMD) so all 38 LDS addresses are loop-invariant and
// hoist into registers; staging uses 8 bumped global pointers. XCD-aware block
// swizzle groups 2 heads per XCD (per-XCD K/V working set 2MB < 4MB L2).
// Swapped QK^T (S^T = mfma(K,Q)) -> lane-local softmax; max3 tree; defer-max.
__global__ __launch_bounds__(256) void attn_fwd(
    const unsigned short* __restrict__ qkv,
    const unsigned short* __restrict__ vt,
    unsigned short* __restrict__ ctx) {
  __shared__ unsigned short Ks[64 * 128];
  __shared__ unsigned short Vs[128 * 64];
  __shared__ unsigned short Ps[4 * 16 * 64];
  const int tid = threadIdx.x;
  const int wave = tid >> 6;
  const int lane = tid & 63;
  const int l15 = lane & 15, l16 = lane >> 4;

  // XCD swizzle: linear wg id (x-fastest), 512 wgs % 8 XCDs == 0 -> bijective.
  // XCD x gets swz in [x*64, x*64+64) = heads {2x, 2x+1}.
  const int wg = blockIdx.y * 32 + blockIdx.x;
  const int swz = (wg & 7) * 64 + (wg >> 3);
  const int h = swz >> 5;
  const int q0 = (swz & 31) * 64 + wave * 16;
  const float SCL = 0.08838834764831845f * 1.4426950408889634f;  // 1/sqrt(128)*log2(e)

  // hoist Q fragments into registers: Q[q0+l15][kk*32 + l16*8 .. +7]
  short8 qf[4];
#pragma unroll
  for (int kk = 0; kk < 4; ++kk)
    qf[kk] = *(const short8*)(qkv + (size_t)(q0 + l15) * QKV_LD + h * HD + kk * 32 + l16 * 8);

  f32x4 acc_o[8] = {};
  float m_r = -1e30f;   // running max (log2 domain), q-row = l15
  float l_r = 0.f;      // running denom, q-row = l15

  // staging pointers (inverse-swizzled source), bumped per tile
  const unsigned short* kp[4];
  const unsigned short* vp[4];
#pragma unroll
  for (int i = 0; i < 4; ++i) {
    int lin = i * 4096 + tid * 16;
    int r = lin >> 8;                       // K tile: 256B rows
    int cb = lin & 255;
    kp[i] = qkv + 2048 + h * HD + (size_t)r * QKV_LD + ((cb ^ ((r & 7) << 4)) >> 1);
    r = lin >> 7;                           // V tile: 128B rows
    cb = lin & 127;
    vp[i] = vt + (size_t)h * HD * T_LEN + (size_t)r * T_LEN + ((cb ^ ((r & 7) << 4)) >> 1);
  }

  const int NT = T_LEN / 64;
  for (int t = 0; t < NT; ++t) {
    // stage tile t (single buffer)
#pragma unroll
    for (int i = 0; i < 4; ++i) {
      GLDS16(kp[i], Ks + i * 2048 + wave * 512);
      GLDS16(vp[i], Vs + i * 2048 + wave * 512);
      kp[i] += 64 * QKV_LD;
      vp[i] += 64;
    }
    __syncthreads();

    // S^T = K Q^T : lane (l15,l16) holds S[kv = c*16 + l16*4 + j][q = l15]
    f32x4 st[4] = {};
#pragma unroll
    for (int c = 0; c < 4; ++c) {
#pragma unroll
      for (int kk = 0; kk < 4; ++kk) {
        int row = c * 16 + l15;
        int cb = kk * 64 + l16 * 16;
        short8 kf = *(const short8*)((const char*)Ks + row * 256 + (cb ^ ((row & 7) << 4)));
        st[c] = mfma16(kf, qf[kk], st[c]);   // swapped operands
      }
    }

    // ---- online softmax, lane-local for q-row l15 (replicated over l16) ----
    // max3 tree: 16 values, depth 3
    float ma = max3f(st[0][0], st[0][1], st[0][2]);
    float mb = max3f(st[0][3], st[1][0], st[1][1]);
    float mc = max3f(st[1][2], st[1][3], st[2][0]);
    float md = max3f(st[2][1], st[2][2], st[2][3]);
    float me = max3f(st[3][0], st[3][1], st[3][2]);
    float pmax = fmaxf(max3f(ma, mb, mc), max3f(md, me, st[3][3]));
    pmax *= SCL;
    pmax = fmaxf(pmax, __shfl_xor(pmax, 16));
    pmax = fmaxf(pmax, __shfl_xor(pmax, 32));

    // defer-max: rescale only when tile max exceeds running max by >8 (log2)
    if (!__all(pmax - m_r <= 8.0f)) {
      float nm = fmaxf(m_r, pmax);
      float corr = __builtin_amdgcn_exp2f(m_r - nm);
      m_r = nm;
      l_r *= corr;
      float cj[4];
#pragma unroll
      for (int j = 0; j < 4; ++j) cj[j] = __shfl(corr, l16 * 4 + j);
#pragma unroll
      for (int d = 0; d < 8; ++d)
#pragma unroll
        for (int j = 0; j < 4; ++j) acc_o[d][j] *= cj[j];
    }

    float p[4][4];
#pragma unroll
    for (int c = 0; c < 4; ++c)
#pragma unroll
      for (int j = 0; j < 4; ++j)
        p[c][j] = __builtin_amdgcn_exp2f(st[c][j] * SCL - m_r);
    // pairwise sum tree
    float s01 = (p[0][0] + p[0][1]) + (p[0][2] + p[0][3]);
    float s23 = (p[1][0] + p[1][1]) + (p[1][2] + p[1][3]);
    float s45 = (p[2][0] + p[2][1]) + (p[2][2] + p[2][3]);
    float s67 = (p[3][0] + p[3][1]) + (p[3][2] + p[3][3]);
    float tsum = (s01 + s23) + (s45 + s67);
    tsum += __shfl_xor(tsum, 16);
    tsum += __shfl_xor(tsum, 32);
    l_r += tsum;

    // ---- P -> LDS: pack bf16 pairs, 4x ds_write_b64, swizzled ----
    char* pbase = (char*)Ps + wave * 2048;
#pragma unroll
    for (int c = 0; c < 4; ++c) {
      uint2v w;
      w.x = (unsigned)f2bf(p[c][0]) | ((unsigned)f2bf(p[c][1]) << 16);
      w.y = (unsigned)f2bf(p[c][2]) | ((unsigned)f2bf(p[c][3]) << 16);
      int off = l15 * 128 + c * 32 + l16 * 8;
      *(uint2v*)(pbase + (off ^ ((l15 & 7) << 4))) = w;
    }

    // ---- ctx += P @ V ----
#pragma unroll
    for (int kk = 0; kk < 2; ++kk) {
      int cb = kk * 64 + l16 * 16;
      short8 pa = *(const short8*)(pbase + l15 * 128 + (cb ^ ((l15 & 7) << 4)));
#pragma unroll
      for (int d = 0; d < 8; ++d) {
        int row = d * 16 + l15;
        short8 vb = *(const short8*)((const char*)Vs + row * 128 + (cb ^ ((row & 7) << 4)));
        acc_o[d] = mfma16(pa, vb, acc_o[d]);
      }
    }

    __syncthreads();   // all waves done reading K/V before next stage
  }

  // epilogue: ctx[q][h*128+d] = acc/l ; l_r lives at lane q=l15, acc rows are
  // q=l16*4+j -> redistribute once via shfl
  float lq[4];
#pragma unroll
  for (int j = 0; j < 4; ++j) lq[j] = 1.0f / __shfl(l_r, l16 * 4 + j);
#pragma unroll
  for (int d = 0; d < 8; ++d)
#pragma unroll
    for (int j = 0; j < 4; ++j) {
      int row = q0 + l16 * 4 + j;
      int col = h * HD + d * 16 + l15;
      ctx[(size_t)row * DIM + col] = f2bf(acc_o[d][j] * lq[j]);
    }
}

// ---------------------------------------------------------------- launcher
extern "C" void kernel_launch(void* const* d_in, const int* in_sizes, int n_in,
                              void* d_out, int out_size, void* d_ws, size_t ws_size,
                              hipStream_t stream) {
  const float* x = (const float*)d_in[0];
  const float* w_in = (const float*)d_in[1];
  const float* w_out = (const float*)d_in[2];

  char* ws = (char*)d_ws;
  unsigned short* xbf  = (unsigned short*)(ws + 0);          //  8 MB
  unsigned short* wibf = (unsigned short*)(ws + 8388608);    // 24 MB
  unsigned short* wobf = (unsigned short*)(ws + 33554432);   //  8 MB
  unsigned short* qkv  = (unsigned short*)(ws + 41943040);   // 24 MB
  unsigned short* ctx  = (unsigned short*)(ws + 67108864);   //  8 MB
  unsigned short* vt   = (unsigned short*)(ws + 75497472);   //  8 MB  (end: 80 MB)

  cast_f32_bf16<<<2048, 256, 0, stream>>>(x, xbf, (T_LEN * DIM) / 4);
  cast_f32_bf16<<<2048, 256, 0, stream>>>(w_in, wibf, (3 * DIM * DIM) / 4);
  cast_f32_bf16<<<2048, 256, 0, stream>>>(w_out, wobf, (DIM * DIM) / 4);

  // qkv = x @ w_in^T   [2048 x 6144]
  gemm_bt_128<1><<<dim3(48, 16), 256, 0, stream>>>(xbf, wibf, (void*)qkv, T_LEN, 3 * DIM, DIM);
  // vt[h][d][s] = V
  transpose_v<<<dim3(32, 16), 256, 0, stream>>>(qkv, vt);
  // attention -> ctx [2048 x 2048] bf16
  attn_fwd<<<dim3(32, 16), 256, 0, stream>>>(qkv, vt, ctx);
  // out = ctx @ w_out^T  (fp32)
  gemm_bt_128<0><<<dim3(16, 16), 256, 0, stream>>>(ctx, wobf, d_out, T_LEN, DIM, DIM);
}